// Round 1
// baseline (1514.305 us; speedup 1.0000x reference)
//
#include <hip/hip_runtime.h>

#define NN 100000
#define NE 1200000
#define NG 2048
#define D 64
#define C 2

__device__ __forceinline__ void atomAdd(float* p, float v) {
    __hip_atomic_fetch_add(p, v, __ATOMIC_RELAXED, __HIP_MEMORY_SCOPE_AGENT);
}

// h0[n, :] = emb[x[n], :]   (float4-vectorized: 16 float4 per node)
__global__ void k_embed(const int* __restrict__ x, const float4* __restrict__ emb,
                        float4* __restrict__ h) {
    int tid = blockIdx.x * blockDim.x + threadIdx.x;
    if (tid >= NN * 16) return;
    int n = tid >> 4;
    int c = tid & 15;
    h[tid] = emb[x[n] * 16 + c];
}

// cnt[dst[e]] += 1
__global__ void k_degree(const int* __restrict__ dst, float* __restrict__ cnt) {
    int e = blockIdx.x * blockDim.x + threadIdx.x;
    if (e < NE) atomAdd(&cnt[dst[e]], 1.0f);
}

// agg[dst[e], d] += h[src[e], d]   one thread per (edge, d)
__global__ void k_scatter(const int* __restrict__ src, const int* __restrict__ dst,
                          const float* __restrict__ h, float* __restrict__ agg) {
    int tid = blockIdx.x * blockDim.x + threadIdx.x;  // < NE*64 = 76.8M, fits in int
    if (tid >= NE * D) return;
    int e = tid >> 6;
    int d = tid & 63;
    atomAdd(&agg[dst[e] * D + d], h[src[e] * D + d]);
}

// hout[n,d] = relu( (agg[n,:]/max(cnt,1)) . Wl[d,:] + bl[d] + hin[n,:] . Wr[d,:] )
// block = 256 threads = 4 nodes x 64 lanes; lane d computes output feature d.
__global__ void k_sage(const float* __restrict__ agg, const float* __restrict__ cnt,
                       const float* __restrict__ hin,
                       const float* __restrict__ Wl, const float* __restrict__ bl,
                       const float* __restrict__ Wr, float* __restrict__ hout) {
    __shared__ float s_agg[4][D];
    __shared__ float s_h[4][D];
    int g = threadIdx.x >> 6;
    int d = threadIdx.x & 63;
    int n = blockIdx.x * 4 + g;   // NN = 100000 divisible by 4: no partial blocks
    s_agg[g][d] = agg[n * D + d];
    s_h[g][d]   = hin[n * D + d];
    __syncthreads();
    float inv = 1.0f / fmaxf(cnt[n], 1.0f);
    float a = 0.f, r = 0.f;
#pragma unroll
    for (int k = 0; k < D; ++k) {
        a += s_agg[g][k] * Wl[d * D + k];   // (agg . Wl_row); scale by inv after (linear)
        r += s_h[g][k]   * Wr[d * D + k];
    }
    float v = a * inv + bl[d] + r;
    hout[n * D + d] = fmaxf(v, 0.f);
}

// pooled[batch[n], d] += h[n, d];  gcnt[batch[n]] += 1 (once per node)
__global__ void k_pool(const int* __restrict__ batch, const float* __restrict__ h,
                       float* __restrict__ pooled, float* __restrict__ gcnt) {
    int tid = blockIdx.x * blockDim.x + threadIdx.x;  // < NN*64
    if (tid >= NN * D) return;
    int n = tid >> 6;
    int d = tid & 63;
    int b = batch[n];
    atomAdd(&pooled[b * D + d], h[tid]);
    if (d == 0) atomAdd(&gcnt[b], 1.0f);
}

// out[g,c] = (pooled[g,:]/max(gcnt,1)) . Wout[c,:] + bout[c]
__global__ void k_final(const float* __restrict__ pooled, const float* __restrict__ gcnt,
                        const float* __restrict__ Wout, const float* __restrict__ bout,
                        float* __restrict__ out) {
    int tid = blockIdx.x * blockDim.x + threadIdx.x;
    if (tid >= NG * C) return;
    int g = tid / C;
    int c = tid % C;
    float inv = 1.0f / fmaxf(gcnt[g], 1.0f);
    float acc = 0.f;
#pragma unroll
    for (int k = 0; k < D; ++k) acc += pooled[g * D + k] * Wout[c * D + k];
    out[tid] = acc * inv + bout[c];
}

extern "C" void kernel_launch(void* const* d_in, const int* in_sizes, int n_in,
                              void* d_out, int out_size, void* d_ws, size_t ws_size,
                              hipStream_t stream) {
    const int*   x     = (const int*)d_in[0];
    const int*   src   = (const int*)d_in[1];          // edge_index[0]
    const int*   dst   = src + NE;                     // edge_index[1]
    const int*   batch = (const int*)d_in[2];
    const float* emb   = (const float*)d_in[3];
    const float* W1l   = (const float*)d_in[4];
    const float* b1l   = (const float*)d_in[5];
    const float* W1r   = (const float*)d_in[6];
    const float* W2l   = (const float*)d_in[7];
    const float* b2l   = (const float*)d_in[8];
    const float* W2r   = (const float*)d_in[9];
    const float* Wout  = (const float*)d_in[10];
    const float* bout  = (const float*)d_in[11];
    float* out = (float*)d_out;

    float* ws     = (float*)d_ws;
    float* agg    = ws;                       // NN*D
    float* cnt    = agg + (size_t)NN * D;     // NN
    float* pooled = cnt + NN;                 // NG*D
    float* gcnt   = pooled + (size_t)NG * D;  // NG
    float* h0     = gcnt + NG;                // NN*D
    float* h1     = h0 + (size_t)NN * D;      // NN*D

    // zero agg + cnt + pooled + gcnt in one contiguous memset
    size_t zero_bytes = ((size_t)NN * D + NN + (size_t)NG * D + NG) * sizeof(float);
    hipMemsetAsync(agg, 0, zero_bytes, stream);

    k_embed<<<(NN * 16 + 255) / 256, 256, 0, stream>>>(x, (const float4*)emb, (float4*)h0);
    k_degree<<<(NE + 255) / 256, 256, 0, stream>>>(dst, cnt);

    // ---- layer 1 ----
    k_scatter<<<(NE * D) / 256, 256, 0, stream>>>(src, dst, h0, agg);
    k_sage<<<NN / 4, 256, 0, stream>>>(agg, cnt, h0, W1l, b1l, W1r, h1);

    // ---- layer 2 ----
    hipMemsetAsync(agg, 0, (size_t)NN * D * sizeof(float), stream);
    k_scatter<<<(NE * D) / 256, 256, 0, stream>>>(src, dst, h1, agg);
    k_sage<<<NN / 4, 256, 0, stream>>>(agg, cnt, h1, W2l, b2l, W2r, h0);  // h0 reused as h2

    // ---- readout ----
    k_pool<<<(NN * D + 255) / 256, 256, 0, stream>>>(batch, h0, pooled, gcnt);
    k_final<<<(NG * C + 255) / 256, 256, 0, stream>>>(pooled, gcnt, Wout, bout, out);
}

// Round 2
// 955.507 us; speedup vs baseline: 1.5848x; 1.5848x over previous
//
#include <hip/hip_runtime.h>

#define NN 100000
#define NE 1200000
#define NG 2048
#define D 64
#define C 2

__device__ __forceinline__ void atomAdd(float* p, float v) {
    __hip_atomic_fetch_add(p, v, __ATOMIC_RELAXED, __HIP_MEMORY_SCOPE_AGENT);
}

// h0[n, :] = emb[x[n], :]   (float4-vectorized: 16 float4 per node)
__global__ void k_embed(const int* __restrict__ x, const float4* __restrict__ emb,
                        float4* __restrict__ h) {
    int tid = blockIdx.x * blockDim.x + threadIdx.x;
    if (tid >= NN * 16) return;
    int n = tid >> 4;
    int c = tid & 15;
    h[tid] = emb[x[n] * 16 + c];
}

// cnt[dst[e]] += 1
__global__ void k_degree(const int* __restrict__ dst, float* __restrict__ cnt) {
    int e = blockIdx.x * blockDim.x + threadIdx.x;
    if (e < NE) atomAdd(&cnt[dst[e]], 1.0f);
}

// agg[dst[e], d] += h[src[e], d]   one thread per (edge, d); wave = 1 edge,
// lanes cover d=0..63 -> both the gather and the atomics are lane-contiguous.
__global__ void k_scatter(const int* __restrict__ src, const int* __restrict__ dst,
                          const float* __restrict__ h, float* __restrict__ agg) {
    int tid = blockIdx.x * blockDim.x + threadIdx.x;  // < NE*64 = 76.8M
    if (tid >= NE * D) return;
    int e = tid >> 6;
    int d = tid & 63;
    atomAdd(&agg[dst[e] * D + d], h[src[e] * D + d]);
}

// hout[n,d] = relu( (agg[n,:]/max(cnt,1)) . Wl[d,:] + bl[d] + hin[n,:] . Wr[d,:] )
//
// Layout: block = 256 threads = 4 waves. Lane d holds rows Wl[d,:], Wr[d,:] in
// registers (32 float4, loaded once per block, amortized over NPW nodes/wave).
// Each wave processes one node at a time; node index is wave-uniform
// (readfirstlane) so agg/h row reads are uniform-address (scalar-load eligible,
// 1 cache line per instruction instead of the 64-line strided gather of R0).
#define NPW 25   // nodes per wave; block covers 100 nodes; grid = NN/100 = 1000
__global__ void k_sage(const float* __restrict__ agg, const float* __restrict__ cnt,
                       const float* __restrict__ hin,
                       const float4* __restrict__ Wl, const float* __restrict__ bl,
                       const float4* __restrict__ Wr, float* __restrict__ hout) {
    int lane = threadIdx.x & 63;
    int wave = threadIdx.x >> 6;

    // per-lane weight rows in registers
    float4 wl[16], wr[16];
#pragma unroll
    for (int i = 0; i < 16; ++i) {
        wl[i] = Wl[lane * 16 + i];
        wr[i] = Wr[lane * 16 + i];
    }
    float bias = bl[lane];

    int n0 = blockIdx.x * (4 * NPW) + wave * NPW;
    for (int j = 0; j < NPW; ++j) {
        int n = __builtin_amdgcn_readfirstlane(n0 + j);  // wave-uniform
        const float4* aRow = (const float4*)(agg + (size_t)n * D);
        const float4* hRow = (const float4*)(hin + (size_t)n * D);
        float inv = 1.0f / fmaxf(cnt[n], 1.0f);
        float a = 0.f, r = 0.f;
#pragma unroll
        for (int k = 0; k < 16; ++k) {
            float4 a4 = aRow[k];
            float4 h4 = hRow[k];
            a += a4.x * wl[k].x + a4.y * wl[k].y + a4.z * wl[k].z + a4.w * wl[k].w;
            r += h4.x * wr[k].x + h4.y * wr[k].y + h4.z * wr[k].z + h4.w * wr[k].w;
        }
        float v = a * inv + bias + r;
        hout[(size_t)n * D + lane] = fmaxf(v, 0.f);
    }
}

// pooled[batch[n], d] += h[n, d];  gcnt[batch[n]] += 1 (once per node)
__global__ void k_pool(const int* __restrict__ batch, const float* __restrict__ h,
                       float* __restrict__ pooled, float* __restrict__ gcnt) {
    int tid = blockIdx.x * blockDim.x + threadIdx.x;  // < NN*64
    if (tid >= NN * D) return;
    int n = tid >> 6;
    int d = tid & 63;
    int b = batch[n];
    atomAdd(&pooled[b * D + d], h[tid]);
    if (d == 0) atomAdd(&gcnt[b], 1.0f);
}

// out[g,c] = (pooled[g,:]/max(gcnt,1)) . Wout[c,:] + bout[c]
__global__ void k_final(const float* __restrict__ pooled, const float* __restrict__ gcnt,
                        const float* __restrict__ Wout, const float* __restrict__ bout,
                        float* __restrict__ out) {
    int tid = blockIdx.x * blockDim.x + threadIdx.x;
    if (tid >= NG * C) return;
    int g = tid / C;
    int c = tid % C;
    float inv = 1.0f / fmaxf(gcnt[g], 1.0f);
    float acc = 0.f;
#pragma unroll
    for (int k = 0; k < D; ++k) acc += pooled[g * D + k] * Wout[c * D + k];
    out[tid] = acc * inv + bout[c];
}

extern "C" void kernel_launch(void* const* d_in, const int* in_sizes, int n_in,
                              void* d_out, int out_size, void* d_ws, size_t ws_size,
                              hipStream_t stream) {
    const int*   x     = (const int*)d_in[0];
    const int*   src   = (const int*)d_in[1];          // edge_index[0]
    const int*   dst   = src + NE;                     // edge_index[1]
    const int*   batch = (const int*)d_in[2];
    const float* emb   = (const float*)d_in[3];
    const float* W1l   = (const float*)d_in[4];
    const float* b1l   = (const float*)d_in[5];
    const float* W1r   = (const float*)d_in[6];
    const float* W2l   = (const float*)d_in[7];
    const float* b2l   = (const float*)d_in[8];
    const float* W2r   = (const float*)d_in[9];
    const float* Wout  = (const float*)d_in[10];
    const float* bout  = (const float*)d_in[11];
    float* out = (float*)d_out;

    float* ws     = (float*)d_ws;
    float* agg    = ws;                       // NN*D
    float* cnt    = agg + (size_t)NN * D;     // NN
    float* pooled = cnt + NN;                 // NG*D
    float* gcnt   = pooled + (size_t)NG * D;  // NG
    float* h0     = gcnt + NG;                // NN*D
    float* h1     = h0 + (size_t)NN * D;      // NN*D

    // zero agg + cnt + pooled + gcnt in one contiguous memset
    size_t zero_bytes = ((size_t)NN * D + NN + (size_t)NG * D + NG) * sizeof(float);
    hipMemsetAsync(agg, 0, zero_bytes, stream);

    k_embed<<<(NN * 16 + 255) / 256, 256, 0, stream>>>(x, (const float4*)emb, (float4*)h0);
    k_degree<<<(NE + 255) / 256, 256, 0, stream>>>(dst, cnt);

    // ---- layer 1 ----
    k_scatter<<<(NE * D) / 256, 256, 0, stream>>>(src, dst, h0, agg);
    k_sage<<<NN / (4 * NPW), 256, 0, stream>>>(agg, cnt, h0, (const float4*)W1l, b1l,
                                               (const float4*)W1r, h1);

    // ---- layer 2 ----
    hipMemsetAsync(agg, 0, (size_t)NN * D * sizeof(float), stream);
    k_scatter<<<(NE * D) / 256, 256, 0, stream>>>(src, dst, h1, agg);
    k_sage<<<NN / (4 * NPW), 256, 0, stream>>>(agg, cnt, h1, (const float4*)W2l, b2l,
                                               (const float4*)W2r, h0);  // h0 reused as h2

    // ---- readout ----
    k_pool<<<(NN * D + 255) / 256, 256, 0, stream>>>(batch, h0, pooled, gcnt);
    k_final<<<(NG * C + 255) / 256, 256, 0, stream>>>(pooled, gcnt, Wout, bout, out);
}